// Round 1
// baseline (159.792 us; speedup 1.0000x reference)
//
#include <hip/hip_runtime.h>
#include <cstdint>

#define NN 2048
#define AD 64
#define HH 8
#define DD 512
#define NEG 0.2f

// ---------------------------------------------------------------------------
// Kernel 1: Q = X@Qw + Qb, K = X@Kw + Kb, V = X@Vw + Vb
// grid 384 = 3 mats x (32 row-groups x 4 col-groups), block 256
// block computes 64 rows x 128 cols; thread tile 8 rows x 4 cols
// ---------------------------------------------------------------------------
__global__ __launch_bounds__(256) void qkv_kernel(
    const float* __restrict__ X,
    const float* __restrict__ Qw, const float* __restrict__ Qb,
    const float* __restrict__ Kw, const float* __restrict__ Kb,
    const float* __restrict__ Vw, const float* __restrict__ Vb,
    float* __restrict__ Q, float* __restrict__ K, float* __restrict__ V) {
  __shared__ float Xs[64][68];
  int t = threadIdx.x;
  int b = blockIdx.x;
  int m = b >> 7;           // 0:Q 1:K 2:V
  int tile = b & 127;
  int r0 = (tile >> 2) * 64;
  int d0 = (tile & 3) * 128;
  const float* W  = (m == 0) ? Qw : (m == 1) ? Kw : Vw;
  const float* Bv = (m == 0) ? Qb : (m == 1) ? Kb : Vb;
  float* O        = (m == 0) ? Q  : (m == 1) ? K  : V;

  for (int idx = t; idx < 64 * 64; idx += 256) {
    int r = idx >> 6, c = idx & 63;
    Xs[r][c] = X[(size_t)(r0 + r) * AD + c];
  }
  __syncthreads();

  int tr = t >> 5;          // 0..7 -> rows tr*8..tr*8+7
  int td = t & 31;          // 0..31 -> cols d0+td*4..+3
  int d = d0 + td * 4;
  float4 bias = *(const float4*)&Bv[d];
  float4 acc[8];
#pragma unroll
  for (int i = 0; i < 8; ++i) acc[i] = bias;
  for (int c = 0; c < 64; ++c) {
    float4 w = *(const float4*)&W[c * DD + d];
#pragma unroll
    for (int i = 0; i < 8; ++i) {
      float x = Xs[tr * 8 + i][c];
      acc[i].x += x * w.x; acc[i].y += x * w.y;
      acc[i].z += x * w.z; acc[i].w += x * w.w;
    }
  }
#pragma unroll
  for (int i = 0; i < 8; ++i) {
    *(float4*)&O[(size_t)(r0 + tr * 8 + i) * DD + d] = acc[i];
  }
}

// ---------------------------------------------------------------------------
// Kernel 2: S1[i,k,h] = sum_d Q[i,d]*a[k,d,h];  S2[j,k,h] = sum_d K[j,d]*a[k,512+d,h]
// layout S1/S2: [i][k*8+h]. grid 256 (8 rows each), block 256.
// thread: (kh = t&63, d-chunk dg = t>>6 of 128), partials reduced via LDS.
// ---------------------------------------------------------------------------
__global__ __launch_bounds__(256) void s12_kernel(
    const float* __restrict__ Q, const float* __restrict__ K,
    const float* __restrict__ A,
    float* __restrict__ S1, float* __restrict__ S2) {
  __shared__ float Qs[8][512];
  __shared__ float Ks[8][512];
  __shared__ float red1[4][8][64];
  __shared__ float red2[4][8][64];
  int t = threadIdx.x;
  int r0 = blockIdx.x * 8;
  for (int idx = t; idx < 8 * 512; idx += 256) {
    int r = idx >> 9, dd = idx & 511;
    Qs[r][dd] = Q[(size_t)(r0 + r) * DD + dd];
    Ks[r][dd] = K[(size_t)(r0 + r) * DD + dd];
  }
  __syncthreads();
  int kh = t & 63;
  int dg = t >> 6;          // 0..3, d range [dg*128, dg*128+128)
  int k = kh >> 3, h = kh & 7;
  float as1[8], as2[8];
#pragma unroll
  for (int i = 0; i < 8; ++i) { as1[i] = 0.f; as2[i] = 0.f; }
  const float* A1 = A + (size_t)k * 1024 * 8 + h;   // a[k][d][h]
  const float* A2 = A1 + 512 * 8;                   // a[k][512+d][h]
  for (int dq = 0; dq < 32; ++dq) {
    int dd = dg * 128 + dq * 4;
    float a10 = A1[(dd + 0) * 8], a11 = A1[(dd + 1) * 8],
          a12 = A1[(dd + 2) * 8], a13 = A1[(dd + 3) * 8];
    float a20 = A2[(dd + 0) * 8], a21 = A2[(dd + 1) * 8],
          a22 = A2[(dd + 2) * 8], a23 = A2[(dd + 3) * 8];
#pragma unroll
    for (int i = 0; i < 8; ++i) {
      float4 q  = *(const float4*)&Qs[i][dd];
      float4 kk = *(const float4*)&Ks[i][dd];
      as1[i] += q.x  * a10 + q.y  * a11 + q.z  * a12 + q.w  * a13;
      as2[i] += kk.x * a20 + kk.y * a21 + kk.z * a22 + kk.w * a23;
    }
  }
#pragma unroll
  for (int i = 0; i < 8; ++i) {
    red1[dg][i][kh] = as1[i];
    red2[dg][i][kh] = as2[i];
  }
  __syncthreads();
  for (int idx = t; idx < 512; idx += 256) {
    int i = idx >> 6, kk2 = idx & 63;
    float v1 = red1[0][i][kk2] + red1[1][i][kk2] + red1[2][i][kk2] + red1[3][i][kk2];
    float v2 = red2[0][i][kk2] + red2[1][i][kk2] + red2[2][i][kk2] + red2[3][i][kk2];
    S1[(size_t)(r0 + i) * 64 + kk2] = v1;
    S2[(size_t)(r0 + i) * 64 + kk2] = v2;
  }
}

// ---------------------------------------------------------------------------
// Kernel 3: fused attention (no max subtraction; exp values bounded ~6e4).
// grid 512 = 256 row-groups (8 rows) x 2 j-halves (1024 j each). block 512.
// Per 64-j tile:
//   phase 1 (wave=row, lane=j): p = exp(valid ? leaky(S1+S2) : 0) -> Ps LDS,
//                               lsum[h] accumulated per-thread.
//   phase 2 (wave=head, lane=dim): acc[r] += Ps[j][h][r] * V[j][h*64+d].
// Writes partial numerators PART[jh] and partial denominators LPART[jh].
// ---------------------------------------------------------------------------
__global__ __launch_bounds__(512) void attn_kernel(
    const int* __restrict__ E,
    const float* __restrict__ S1, const float* __restrict__ S2,
    const float* __restrict__ V,
    float* __restrict__ PART, float* __restrict__ LPART) {
  __shared__ float s1s[8][64];
  __shared__ int   ei[8][64];
  __shared__ float s2s[64][65];
  __shared__ __align__(16) float Ps[64][68];   // [j][h*8 + r], pad to 68 (16B rows)
  int t = threadIdx.x;
  int bx = blockIdx.x;
  int rg = bx >> 1, jh = bx & 1;
  int r0 = rg * 8;
  size_t jbase0 = (size_t)jh * 1024;

  {
    int r = t >> 6, kh = t & 63;
    s1s[r][kh] = S1[(size_t)(r0 + r) * 64 + kh];
  }
  float lsum[8];
  float acc[8];
#pragma unroll
  for (int i = 0; i < 8; ++i) { lsum[i] = 0.f; acc[i] = 0.f; }
  int wid = t >> 6;   // wave id 0..7
  int lane = t & 63;

#pragma unroll 1
  for (int tile = 0; tile < 16; ++tile) {
    size_t jb = jbase0 + (size_t)tile * 64;
    // stage edges row-tile + S2 tile (phase2 of prev tile doesn't touch these)
    ei[wid][lane] = E[(size_t)(r0 + wid) * NN + jb + lane];
    for (int idx = t; idx < 64 * 64; idx += 512) {
      int j = idx >> 6, c = idx & 63;
      s2s[j][c] = S2[(jb + j) * 64 + c];
    }
    __syncthreads();   // stage done; also fences prev phase2 reads of Ps
    // ---- phase 1: scores -> Ps
    {
      int r = wid, j = lane;
      int edge = ei[r][j];
      bool valid = edge >= 0;
      int k = edge < 0 ? 0 : (edge > 7 ? 7 : edge);
      const float* s1p = &s1s[r][k * 8];
      const float* s2p = &s2s[j][k * 8];
#pragma unroll
      for (int h = 0; h < 8; ++h) {
        float s = s1p[h] + s2p[h];
        float e = fmaxf(s, NEG * s);          // leaky_relu
        e = valid ? e : 0.0f;                 // invalid edge -> e = 0 (exp = 1!)
        float p = __expf(e);
        lsum[h] += p;
        Ps[j][h * 8 + r] = p;
      }
    }
    __syncthreads();
    // ---- phase 2: accumulate numerator
    {
      int h = wid, ddim = lane;
      const float* vp = &V[jb * DD + h * 64 + ddim];
#pragma unroll 4
      for (int j = 0; j < 64; ++j) {
        float v = vp[(size_t)j * DD];
        float4 pa = *(const float4*)&Ps[j][h * 8];
        float4 pb = *(const float4*)&Ps[j][h * 8 + 4];
        acc[0] += pa.x * v; acc[1] += pa.y * v;
        acc[2] += pa.z * v; acc[3] += pa.w * v;
        acc[4] += pb.x * v; acc[5] += pb.y * v;
        acc[6] += pb.z * v; acc[7] += pb.w * v;
      }
    }
  }

  // reduce lsum over 64 lanes (wave wid owns row r0+wid)
#pragma unroll
  for (int h = 0; h < 8; ++h) {
    float v = lsum[h];
#pragma unroll
    for (int m = 32; m > 0; m >>= 1) v += __shfl_xor(v, m);
    lsum[h] = v;
  }
  if (lane == 0) {
    float* lp = LPART + (size_t)jh * NN * 8 + (size_t)(r0 + wid) * 8;
#pragma unroll
    for (int h = 0; h < 8; ++h) lp[h] = lsum[h];
  }
  // write partial numerators: thread (h=wid, d=lane), rows 0..7
  {
    float* pp = PART + (size_t)jh * NN * DD + (size_t)r0 * DD + wid * 64 + lane;
#pragma unroll
    for (int rr = 0; rr < 8; ++rr) pp[(size_t)rr * DD] = acc[rr];
  }
}

// ---------------------------------------------------------------------------
// Kernel 4: combine j-halves, divide by denominator, project with Pw + Pb.
// grid 256 (8 rows each), block 256.
// ---------------------------------------------------------------------------
__global__ __launch_bounds__(256) void proj_kernel(
    const float* __restrict__ PART, const float* __restrict__ LPART,
    const float* __restrict__ Pw, const float* __restrict__ Pb,
    float* __restrict__ out) {
  __shared__ __align__(16) float preS[8][512];
  __shared__ float linv[8][8];
  int t = threadIdx.x;
  int r0 = blockIdx.x * 8;
  if (t < 64) {
    int i = t >> 3, h = t & 7;
    float s = LPART[(size_t)(r0 + i) * 8 + h] +
              LPART[(size_t)NN * 8 + (size_t)(r0 + i) * 8 + h];
    linv[i][h] = 1.0f / s;
  }
  __syncthreads();
  for (int idx = t; idx < 8 * 512; idx += 256) {
    int i = idx >> 9, hd = idx & 511;
    float v = PART[(size_t)(r0 + i) * DD + hd] +
              PART[(size_t)NN * DD + (size_t)(r0 + i) * DD + hd];
    preS[i][hd] = v * linv[i][hd >> 6];
  }
  __syncthreads();
  int c = t & 63, rq = t >> 6;   // rq 0..3, rows rq and rq+4
  float acc0 = Pb[c], acc1 = Pb[c];
  for (int hq = 0; hq < 128; ++hq) {
    int hd = hq * 4;
    float4 p0 = *(const float4*)&preS[rq][hd];
    float4 p1 = *(const float4*)&preS[rq + 4][hd];
    float w0 = Pw[(hd + 0) * 64 + c];
    float w1 = Pw[(hd + 1) * 64 + c];
    float w2 = Pw[(hd + 2) * 64 + c];
    float w3 = Pw[(hd + 3) * 64 + c];
    acc0 += p0.x * w0 + p0.y * w1 + p0.z * w2 + p0.w * w3;
    acc1 += p1.x * w0 + p1.y * w1 + p1.z * w2 + p1.w * w3;
  }
  out[(size_t)(r0 + rq) * 64 + c] = acc0;
  out[(size_t)(r0 + rq + 4) * 64 + c] = acc1;
}

// ---------------------------------------------------------------------------
extern "C" void kernel_launch(void* const* d_in, const int* in_sizes, int n_in,
                              void* d_out, int out_size, void* d_ws, size_t ws_size,
                              hipStream_t stream) {
  const float* X  = (const float*)d_in[0];
  const int*   E  = (const int*)d_in[1];
  const float* Qw = (const float*)d_in[2];
  const float* Qb = (const float*)d_in[3];
  const float* Kw = (const float*)d_in[4];
  const float* Kb = (const float*)d_in[5];
  const float* Vw = (const float*)d_in[6];
  const float* Vb = (const float*)d_in[7];
  const float* A  = (const float*)d_in[8];
  const float* Pw = (const float*)d_in[9];
  const float* Pb = (const float*)d_in[10];
  float* out = (float*)d_out;

  float* ws = (float*)d_ws;
  const size_t ND = (size_t)NN * DD;
  float* Q     = ws;                    // ND
  float* K     = Q + ND;                // ND
  float* V     = K + ND;                // ND
  float* S1    = V + ND;                // N*64
  float* S2    = S1 + (size_t)NN * 64;  // N*64
  float* PART  = S2 + (size_t)NN * 64;  // 2*ND
  float* LPART = PART + 2 * ND;         // 2*N*8

  qkv_kernel<<<384, 256, 0, stream>>>(X, Qw, Qb, Kw, Kb, Vw, Vb, Q, K, V);
  s12_kernel<<<256, 256, 0, stream>>>(Q, K, A, S1, S2);
  attn_kernel<<<512, 512, 0, stream>>>(E, S1, S2, V, PART, LPART);
  proj_kernel<<<256, 256, 0, stream>>>(PART, LPART, Pw, Pb, out);
}

// Round 2
// 105.202 us; speedup vs baseline: 1.5189x; 1.5189x over previous
//
#include <hip/hip_runtime.h>

#define NN 2048
#define AD 64
#define HH 8
#define DD 512
#define NEG 0.2f

typedef float f32x4 __attribute__((ext_vector_type(4)));
typedef _Float16 half8 __attribute__((ext_vector_type(8)));
typedef unsigned short u16;
typedef u16 u16x8 __attribute__((ext_vector_type(8)));

// ---------------------------------------------------------------------------
// Kernel 1: Q = X@Qw + Qb, K = X@Kw + Kb, V = X@Vw + Vb
// grid 384 = 3 mats x (32 row-groups x 4 col-groups), block 256
// ---------------------------------------------------------------------------
__global__ __launch_bounds__(256) void qkv_kernel(
    const float* __restrict__ X,
    const float* __restrict__ Qw, const float* __restrict__ Qb,
    const float* __restrict__ Kw, const float* __restrict__ Kb,
    const float* __restrict__ Vw, const float* __restrict__ Vb,
    float* __restrict__ Q, float* __restrict__ K, float* __restrict__ V) {
  __shared__ float Xs[64][68];
  int t = threadIdx.x;
  int b = blockIdx.x;
  int m = b >> 7;           // 0:Q 1:K 2:V
  int tile = b & 127;
  int r0 = (tile >> 2) * 64;
  int d0 = (tile & 3) * 128;
  const float* W  = (m == 0) ? Qw : (m == 1) ? Kw : Vw;
  const float* Bv = (m == 0) ? Qb : (m == 1) ? Kb : Vb;
  float* O        = (m == 0) ? Q  : (m == 1) ? K  : V;

  for (int idx = t; idx < 64 * 64; idx += 256) {
    int r = idx >> 6, c = idx & 63;
    Xs[r][c] = X[(size_t)(r0 + r) * AD + c];
  }
  __syncthreads();

  int tr = t >> 5;
  int td = t & 31;
  int d = d0 + td * 4;
  float4 bias = *(const float4*)&Bv[d];
  float4 acc[8];
#pragma unroll
  for (int i = 0; i < 8; ++i) acc[i] = bias;
  for (int c = 0; c < 64; ++c) {
    float4 w = *(const float4*)&W[c * DD + d];
#pragma unroll
    for (int i = 0; i < 8; ++i) {
      float x = Xs[tr * 8 + i][c];
      acc[i].x += x * w.x; acc[i].y += x * w.y;
      acc[i].z += x * w.z; acc[i].w += x * w.w;
    }
  }
#pragma unroll
  for (int i = 0; i < 8; ++i) {
    *(float4*)&O[(size_t)(r0 + tr * 8 + i) * DD + d] = acc[i];
  }
}

// ---------------------------------------------------------------------------
// Kernel 2: S1[i][k*8+h], S2[j][k*8+h]  (unchanged from R0)
// ---------------------------------------------------------------------------
__global__ __launch_bounds__(256) void s12_kernel(
    const float* __restrict__ Q, const float* __restrict__ K,
    const float* __restrict__ A,
    float* __restrict__ S1, float* __restrict__ S2) {
  __shared__ float Qs[8][512];
  __shared__ float Ks[8][512];
  __shared__ float red1[4][8][64];
  __shared__ float red2[4][8][64];
  int t = threadIdx.x;
  int r0 = blockIdx.x * 8;
  for (int idx = t; idx < 8 * 512; idx += 256) {
    int r = idx >> 9, dd = idx & 511;
    Qs[r][dd] = Q[(size_t)(r0 + r) * DD + dd];
    Ks[r][dd] = K[(size_t)(r0 + r) * DD + dd];
  }
  __syncthreads();
  int kh = t & 63;
  int dg = t >> 6;
  int k = kh >> 3, h = kh & 7;
  float as1[8], as2[8];
#pragma unroll
  for (int i = 0; i < 8; ++i) { as1[i] = 0.f; as2[i] = 0.f; }
  const float* A1 = A + (size_t)k * 1024 * 8 + h;
  const float* A2 = A1 + 512 * 8;
  for (int dq = 0; dq < 32; ++dq) {
    int dd = dg * 128 + dq * 4;
    float a10 = A1[(dd + 0) * 8], a11 = A1[(dd + 1) * 8],
          a12 = A1[(dd + 2) * 8], a13 = A1[(dd + 3) * 8];
    float a20 = A2[(dd + 0) * 8], a21 = A2[(dd + 1) * 8],
          a22 = A2[(dd + 2) * 8], a23 = A2[(dd + 3) * 8];
#pragma unroll
    for (int i = 0; i < 8; ++i) {
      float4 q  = *(const float4*)&Qs[i][dd];
      float4 kk = *(const float4*)&Ks[i][dd];
      as1[i] += q.x  * a10 + q.y  * a11 + q.z  * a12 + q.w  * a13;
      as2[i] += kk.x * a20 + kk.y * a21 + kk.z * a22 + kk.w * a23;
    }
  }
#pragma unroll
  for (int i = 0; i < 8; ++i) {
    red1[dg][i][kh] = as1[i];
    red2[dg][i][kh] = as2[i];
  }
  __syncthreads();
  for (int idx = t; idx < 512; idx += 256) {
    int i = idx >> 6, kk2 = idx & 63;
    float v1 = red1[0][i][kk2] + red1[1][i][kk2] + red1[2][i][kk2] + red1[3][i][kk2];
    float v2 = red2[0][i][kk2] + red2[1][i][kk2] + red2[2][i][kk2] + red2[3][i][kk2];
    S1[(size_t)(r0 + i) * 64 + kk2] = v1;
    S2[(size_t)(r0 + i) * 64 + kk2] = v2;
  }
}

// ---------------------------------------------------------------------------
// Kernel 2b: VtH[d][j] = f16(V[j][d])   (transposed f16 copy of V for MFMA B)
// grid 256 = 32 j-tiles x 8 d-tiles of 64x64; block 256
// ---------------------------------------------------------------------------
__global__ __launch_bounds__(256) void vsplit_kernel(
    const float* __restrict__ V, u16* __restrict__ VtH) {
  __shared__ float tile[64][65];
  int t = threadIdx.x;
  int bj = blockIdx.x & 31, bd = blockIdx.x >> 5;
  int j0 = bj * 64, d0 = bd * 64;
  {
    int j = t >> 2, c0 = (t & 3) * 16;
#pragma unroll
    for (int cc = 0; cc < 16; cc += 4) {
      float4 v = *(const float4*)&V[(size_t)(j0 + j) * DD + d0 + c0 + cc];
      tile[j][c0 + cc + 0] = v.x; tile[j][c0 + cc + 1] = v.y;
      tile[j][c0 + cc + 2] = v.z; tile[j][c0 + cc + 3] = v.w;
    }
  }
  __syncthreads();
  {
    int d = t >> 2, g = t & 3;
    u16x8 o0, o1;
#pragma unroll
    for (int jj = 0; jj < 8; ++jj) {
      _Float16 hf = (_Float16)tile[g * 16 + jj][d];
      o0[jj] = __builtin_bit_cast(u16, hf);
    }
#pragma unroll
    for (int jj = 0; jj < 8; ++jj) {
      _Float16 hf = (_Float16)tile[g * 16 + 8 + jj][d];
      o1[jj] = __builtin_bit_cast(u16, hf);
    }
    u16* out = &VtH[(size_t)(d0 + d) * NN + j0 + g * 16];
    *(u16x8*)out = o0;
    *(u16x8*)(out + 8) = o1;
  }
}

// ---------------------------------------------------------------------------
// Kernel 3: MFMA attention.
// grid 256 = 64 i-tiles (32 rows) x 4 j-chunks (512 j). block 512 = 8 waves.
// Wave w = head w. Per j-tile (64): per lane, scores for
//   (i = m*16 + lane&15, j = s*32 + (lane>>4)*8 + e)  -> exactly the
//   mfma_f32_16x16x32_f16 A-fragment layout. B = VtH[d][j] 16B loads.
// p scaled by 1/16 into f16 (max p ~8e4 -> 5e3, f16-safe; x16 restored in proj).
// Denominator lsum kept in exact fp32.
// ---------------------------------------------------------------------------
__global__ __launch_bounds__(512, 2) void attn_mfma_kernel(
    const int* __restrict__ E,
    const float* __restrict__ S1, const float* __restrict__ S2,
    const u16* __restrict__ VtH,
    float* __restrict__ PART, float* __restrict__ LPART) {
  __shared__ float s1p[8][32][9];   // [h][i_local][k]
  __shared__ float s2p[8][64][9];   // [h][j_local][k]
  int t = threadIdx.x;
  int w = t >> 6, lane = t & 63;
  int li = lane & 15, q = lane >> 4;
  int bx = blockIdx.x;
  int it = bx >> 2, ch = bx & 3;
  int i0 = it * 32;
  int jch = ch * 512;

  // stage s1p once (S1 rows i0..i0+31)
  {
    int i = t >> 4, kh0 = (t & 15) * 4;
    float4 v = *(const float4*)&S1[(size_t)(i0 + i) * 64 + kh0];
    float vv[4] = {v.x, v.y, v.z, v.w};
#pragma unroll
    for (int c = 0; c < 4; ++c) {
      int kh = kh0 + c;
      s1p[kh & 7][i][kh >> 3] = vv[c];
    }
  }

  f32x4 acc[2][4];
#pragma unroll
  for (int m = 0; m < 2; ++m)
#pragma unroll
    for (int n = 0; n < 4; ++n) acc[m][n] = (f32x4){0.f, 0.f, 0.f, 0.f};
  float lsum0 = 0.f, lsum1 = 0.f;

#pragma unroll 1
  for (int jt = 0; jt < 8; ++jt) {
    int jb = jch + jt * 64;
    // stage s2p for this tile
    {
      int j = t >> 3, k = t & 7;
      const float* row = &S2[(size_t)(jb + j) * 64 + k * 8];
      float4 u0 = *(const float4*)row;
      float4 u1 = *(const float4*)(row + 4);
      s2p[0][j][k] = u0.x; s2p[1][j][k] = u0.y;
      s2p[2][j][k] = u0.z; s2p[3][j][k] = u0.w;
      s2p[4][j][k] = u1.x; s2p[5][j][k] = u1.y;
      s2p[6][j][k] = u1.z; s2p[7][j][k] = u1.w;
    }
    __syncthreads();

    // B fragments (issue early; L2-resident VtH)
    half8 bfrag[4][2];
#pragma unroll
    for (int n = 0; n < 4; ++n)
#pragma unroll
      for (int s = 0; s < 2; ++s) {
        const u16* p = &VtH[(size_t)(w * 64 + n * 16 + li) * NN + jb + s * 32 + q * 8];
        bfrag[n][s] = *(const half8*)p;
      }

    // scores -> A fragments
    half8 afrag[2][2];
#pragma unroll
    for (int m = 0; m < 2; ++m) {
      int i = m * 16 + li;
      const float* s1row = &s1p[w][i][0];
#pragma unroll
      for (int s = 0; s < 2; ++s) {
        int j0 = s * 32 + q * 8;
        const int* erow = &E[(size_t)(i0 + i) * NN + jb + j0];
        int4 e0 = *(const int4*)erow;
        int4 e1 = *(const int4*)(erow + 4);
        int ed[8] = {e0.x, e0.y, e0.z, e0.w, e1.x, e1.y, e1.z, e1.w};
        half8 af;
        float ls = 0.f;
#pragma unroll
        for (int e = 0; e < 8; ++e) {
          int edge = ed[e];
          int k = min(max(edge, 0), 7);
          float sv = s1row[k] + s2p[w][j0 + e][k];
          float ev = fmaxf(sv, NEG * sv);
          ev = (edge >= 0) ? ev : 0.0f;
          float pv = __expf(ev);
          ls += pv;
          af[e] = (_Float16)(pv * 0.0625f);
        }
        if (m == 0) lsum0 += ls; else lsum1 += ls;
        afrag[m][s] = af;
      }
    }

    // MFMA: acc[m][n] += A[m][s] x B[n][s]
#pragma unroll
    for (int m = 0; m < 2; ++m)
#pragma unroll
      for (int n = 0; n < 4; ++n)
#pragma unroll
        for (int s = 0; s < 2; ++s)
          acc[m][n] = __builtin_amdgcn_mfma_f32_16x16x32_f16(
              afrag[m][s], bfrag[n][s], acc[m][n], 0, 0, 0);

    __syncthreads();
  }

  // denominator: lanes {li, li+16, li+32, li+48} share row i -> reduce over q
  lsum0 += __shfl_xor(lsum0, 16); lsum0 += __shfl_xor(lsum0, 32);
  lsum1 += __shfl_xor(lsum1, 16); lsum1 += __shfl_xor(lsum1, 32);
  if (q == 0) {
    LPART[((size_t)ch * NN + i0 + li) * 8 + w]      = lsum0;
    LPART[((size_t)ch * NN + i0 + 16 + li) * 8 + w] = lsum1;
  }

  // store partial numerators. C layout: col = lane&15, row = (lane>>4)*4 + reg
  float* base = PART + (size_t)ch * NN * DD;
#pragma unroll
  for (int m = 0; m < 2; ++m)
#pragma unroll
    for (int n = 0; n < 4; ++n) {
#pragma unroll
      for (int r = 0; r < 4; ++r) {
        int row = i0 + m * 16 + q * 4 + r;
        int col = w * 64 + n * 16 + li;
        base[(size_t)row * DD + col] = acc[m][n][r];
      }
    }
}

// ---------------------------------------------------------------------------
// Kernel 4: combine 4 j-chunk partials, divide by denominator (x16 for the
// f16 P scaling), project with Pw + Pb. grid 256 (8 rows), block 256.
// ---------------------------------------------------------------------------
__global__ __launch_bounds__(256) void proj_kernel(
    const float* __restrict__ PART, const float* __restrict__ LPART,
    const float* __restrict__ Pw, const float* __restrict__ Pb,
    float* __restrict__ out) {
  __shared__ __align__(16) float preS[8][512];
  __shared__ float linv[8][8];
  int t = threadIdx.x;
  int r0 = blockIdx.x * 8;
  if (t < 64) {
    int i = t >> 3, h = t & 7;
    float s = 0.f;
#pragma unroll
    for (int c = 0; c < 4; ++c)
      s += LPART[(size_t)c * NN * 8 + (size_t)(r0 + i) * 8 + h];
    linv[i][h] = 16.0f / s;
  }
  __syncthreads();
  for (int idx = t; idx < 8 * 512; idx += 256) {
    int i = idx >> 9, hd = idx & 511;
    float v = 0.f;
#pragma unroll
    for (int c = 0; c < 4; ++c)
      v += PART[(size_t)c * NN * DD + (size_t)(r0 + i) * DD + hd];
    preS[i][hd] = v * linv[i][hd >> 6];
  }
  __syncthreads();
  int c = t & 63, rq = t >> 6;
  float acc0 = Pb[c], acc1 = Pb[c];
  for (int hq = 0; hq < 128; ++hq) {
    int hd = hq * 4;
    float4 p0 = *(const float4*)&preS[rq][hd];
    float4 p1 = *(const float4*)&preS[rq + 4][hd];
    float w0 = Pw[(hd + 0) * 64 + c];
    float w1 = Pw[(hd + 1) * 64 + c];
    float w2 = Pw[(hd + 2) * 64 + c];
    float w3 = Pw[(hd + 3) * 64 + c];
    acc0 += p0.x * w0 + p0.y * w1 + p0.z * w2 + p0.w * w3;
    acc1 += p1.x * w0 + p1.y * w1 + p1.z * w2 + p1.w * w3;
  }
  out[(size_t)(r0 + rq) * 64 + c] = acc0;
  out[(size_t)(r0 + rq + 4) * 64 + c] = acc1;
}

// ---------------------------------------------------------------------------
extern "C" void kernel_launch(void* const* d_in, const int* in_sizes, int n_in,
                              void* d_out, int out_size, void* d_ws, size_t ws_size,
                              hipStream_t stream) {
  const float* X  = (const float*)d_in[0];
  const int*   E  = (const int*)d_in[1];
  const float* Qw = (const float*)d_in[2];
  const float* Qb = (const float*)d_in[3];
  const float* Kw = (const float*)d_in[4];
  const float* Kb = (const float*)d_in[5];
  const float* Vw = (const float*)d_in[6];
  const float* Vb = (const float*)d_in[7];
  const float* A  = (const float*)d_in[8];
  const float* Pw = (const float*)d_in[9];
  const float* Pb = (const float*)d_in[10];
  float* out = (float*)d_out;

  float* ws = (float*)d_ws;
  const size_t ND = (size_t)NN * DD;            // 1M floats
  // Region layout (floats). PART aliases Q/K/V (dead by the time attn runs).
  float* Q     = ws;                            // [0, 1M)
  float* K     = ws + ND;                       // [1M, 2M)
  float* V     = ws + 2 * ND;                   // [2M, 3M)
  float* PART  = ws;                            // [0, 4M)  (4 chunks x 1M)
  float* S1    = ws + 4 * ND;                   // 128K
  float* S2    = S1 + (size_t)NN * 64;          // 128K
  u16*   VtH   = (u16*)(S2 + (size_t)NN * 64);  // 1M u16 = 512K floats
  float* LPART = (float*)(VtH + (size_t)DD * NN); // 64K floats

  qkv_kernel<<<384, 256, 0, stream>>>(X, Qw, Qb, Kw, Kb, Vw, Vb, Q, K, V);
  s12_kernel<<<256, 256, 0, stream>>>(Q, K, A, S1, S2);
  vsplit_kernel<<<256, 256, 0, stream>>>(V, VtH);
  attn_mfma_kernel<<<256, 512, 0, stream>>>(E, S1, S2, VtH, PART, LPART);
  proj_kernel<<<256, 256, 0, stream>>>(PART, LPART, Pw, Pb, out);
}

// Round 3
// 97.013 us; speedup vs baseline: 1.6471x; 1.0844x over previous
//
#include <hip/hip_runtime.h>

#define NN 2048
#define AD 64
#define HH 8
#define DD 512
#define NEG 0.2f

typedef float f32x4 __attribute__((ext_vector_type(4)));
typedef _Float16 half8 __attribute__((ext_vector_type(8)));
typedef unsigned short u16;
typedef u16 u16x8 __attribute__((ext_vector_type(8)));

// ---------------------------------------------------------------------------
// Kernel 1: Q = X@Qw + Qb, K = X@Kw + Kb, VtH = f16(X@Vw + Vb)^T
// grid 384 = 3 mats x (32 row-groups x 4 col-groups), block 256
// m==2 (V) writes the transposed f16 VtH[d][j] directly; fp32 V never exists.
// ---------------------------------------------------------------------------
__global__ __launch_bounds__(256) void qkv_kernel(
    const float* __restrict__ X,
    const float* __restrict__ Qw, const float* __restrict__ Qb,
    const float* __restrict__ Kw, const float* __restrict__ Kb,
    const float* __restrict__ Vw, const float* __restrict__ Vb,
    float* __restrict__ Q, float* __restrict__ K, u16* __restrict__ VtH) {
  __shared__ float Xs[64][68];
  int t = threadIdx.x;
  int b = blockIdx.x;
  int m = b >> 7;           // 0:Q 1:K 2:V
  int tile = b & 127;
  int r0 = (tile >> 2) * 64;
  int d0 = (tile & 3) * 128;
  const float* W  = (m == 0) ? Qw : (m == 1) ? Kw : Vw;
  const float* Bv = (m == 0) ? Qb : (m == 1) ? Kb : Vb;

  for (int idx = t; idx < 64 * 64; idx += 256) {
    int r = idx >> 6, c = idx & 63;
    Xs[r][c] = X[(size_t)(r0 + r) * AD + c];
  }
  __syncthreads();

  int tr = t >> 5;          // 0..7 -> rows tr*8..tr*8+7
  int td = t & 31;
  int d = d0 + td * 4;
  float4 bias = *(const float4*)&Bv[d];
  float4 acc[8];
#pragma unroll
  for (int i = 0; i < 8; ++i) acc[i] = bias;
  for (int c = 0; c < 64; ++c) {
    float4 w = *(const float4*)&W[c * DD + d];
#pragma unroll
    for (int i = 0; i < 8; ++i) {
      float x = Xs[tr * 8 + i][c];
      acc[i].x += x * w.x; acc[i].y += x * w.y;
      acc[i].z += x * w.z; acc[i].w += x * w.w;
    }
  }
  if (m == 2) {
    // transposed f16 store: thread owns 8 consecutive j (rows) x 4 d (cols)
#pragma unroll
    for (int c = 0; c < 4; ++c) {
      u16x8 o;
#pragma unroll
      for (int i = 0; i < 8; ++i) {
        float fv = (c == 0) ? acc[i].x : (c == 1) ? acc[i].y
                 : (c == 2) ? acc[i].z : acc[i].w;
        _Float16 hf = (_Float16)fv;
        o[i] = __builtin_bit_cast(u16, hf);
      }
      *(u16x8*)&VtH[(size_t)(d + c) * NN + r0 + tr * 8] = o;
    }
  } else {
    float* O = (m == 0) ? Q : K;
#pragma unroll
    for (int i = 0; i < 8; ++i) {
      *(float4*)&O[(size_t)(r0 + tr * 8 + i) * DD + d] = acc[i];
    }
  }
}

// ---------------------------------------------------------------------------
// Kernel 2: S1[i][k*8+h], S2[j][k*8+h]. grid 512 (4 rows each), block 256.
// ---------------------------------------------------------------------------
__global__ __launch_bounds__(256) void s12_kernel(
    const float* __restrict__ Q, const float* __restrict__ K,
    const float* __restrict__ A,
    float* __restrict__ S1, float* __restrict__ S2) {
  __shared__ float Qs[4][512];
  __shared__ float Ks[4][512];
  __shared__ float red1[4][4][64];
  __shared__ float red2[4][4][64];
  int t = threadIdx.x;
  int r0 = blockIdx.x * 4;
  for (int idx = t; idx < 4 * 128; idx += 256) {
    int r = idx >> 7, dd = (idx & 127) * 4;
    *(float4*)&Qs[r][dd] = *(const float4*)&Q[(size_t)(r0 + r) * DD + dd];
    *(float4*)&Ks[r][dd] = *(const float4*)&K[(size_t)(r0 + r) * DD + dd];
  }
  __syncthreads();
  int kh = t & 63;
  int dg = t >> 6;          // 0..3, d range [dg*128, dg*128+128)
  int k = kh >> 3, h = kh & 7;
  float as1[4], as2[4];
#pragma unroll
  for (int i = 0; i < 4; ++i) { as1[i] = 0.f; as2[i] = 0.f; }
  const float* A1 = A + (size_t)k * 1024 * 8 + h;
  const float* A2 = A1 + 512 * 8;
  for (int dq = 0; dq < 32; ++dq) {
    int dd = dg * 128 + dq * 4;
    float a10 = A1[(dd + 0) * 8], a11 = A1[(dd + 1) * 8],
          a12 = A1[(dd + 2) * 8], a13 = A1[(dd + 3) * 8];
    float a20 = A2[(dd + 0) * 8], a21 = A2[(dd + 1) * 8],
          a22 = A2[(dd + 2) * 8], a23 = A2[(dd + 3) * 8];
#pragma unroll
    for (int i = 0; i < 4; ++i) {
      float4 q  = *(const float4*)&Qs[i][dd];
      float4 kk = *(const float4*)&Ks[i][dd];
      as1[i] += q.x  * a10 + q.y  * a11 + q.z  * a12 + q.w  * a13;
      as2[i] += kk.x * a20 + kk.y * a21 + kk.z * a22 + kk.w * a23;
    }
  }
#pragma unroll
  for (int i = 0; i < 4; ++i) {
    red1[dg][i][kh] = as1[i];
    red2[dg][i][kh] = as2[i];
  }
  __syncthreads();
  {
    int i = t >> 6, kk2 = t & 63;
    float v1 = red1[0][i][kk2] + red1[1][i][kk2] + red1[2][i][kk2] + red1[3][i][kk2];
    float v2 = red2[0][i][kk2] + red2[1][i][kk2] + red2[2][i][kk2] + red2[3][i][kk2];
    S1[(size_t)(r0 + i) * 64 + kk2] = v1;
    S2[(size_t)(r0 + i) * 64 + kk2] = v2;
  }
}

// ---------------------------------------------------------------------------
// Kernel 3: MFMA attention.
// grid 512 = 128 i-tiles (16 rows) x 4 j-chunks (512 j). block 512 = 8 waves.
// Wave w = head w. Lane (li = lane&15, q = lane>>4).
// Per 64-j tile: scores for (i = li, j = s*32 + q*8 + e) = the
// mfma_f32_16x16x32_f16 A-fragment layout; B = VtH[d][j] 16B loads.
// E loads for tile t+1 are issued before scoring tile t (latency overlap).
// p scaled 1/16 into f16; denominator exact fp32.
// ---------------------------------------------------------------------------
__global__ __launch_bounds__(512, 4) void attn_mfma_kernel(
    const int* __restrict__ E,
    const float* __restrict__ S1, const float* __restrict__ S2,
    const u16* __restrict__ VtH,
    float* __restrict__ PART, float* __restrict__ LPART) {
  __shared__ float s1p[8][16][9];   // [h][i_local][k]
  __shared__ float s2p[8][64][9];   // [h][j_local][k]
  int t = threadIdx.x;
  int w = t >> 6, lane = t & 63;
  int li = lane & 15, q = lane >> 4;
  int bx = blockIdx.x;
  int it = bx >> 2, ch = bx & 3;
  int i0 = it * 16;
  int jch = ch * 512;

  if (t < 256) {
    int i = t >> 4, kh0 = (t & 15) * 4;
    float4 v = *(const float4*)&S1[(size_t)(i0 + i) * 64 + kh0];
    float vv[4] = {v.x, v.y, v.z, v.w};
#pragma unroll
    for (int c = 0; c < 4; ++c) {
      int kh = kh0 + c;
      s1p[kh & 7][i][kh >> 3] = vv[c];
    }
  }

  f32x4 acc[4];
#pragma unroll
  for (int n = 0; n < 4; ++n) acc[n] = (f32x4){0.f, 0.f, 0.f, 0.f};
  float lsum = 0.f;

  const int* Erow = E + (size_t)(i0 + li) * NN;
  // prefetch E for tile 0
  int4 pa0 = *(const int4*)(Erow + jch + q * 8);
  int4 pa1 = *(const int4*)(Erow + jch + q * 8 + 4);
  int4 pb0 = *(const int4*)(Erow + jch + 32 + q * 8);
  int4 pb1 = *(const int4*)(Erow + jch + 32 + q * 8 + 4);

#pragma unroll 1
  for (int jt = 0; jt < 8; ++jt) {
    int jb = jch + jt * 64;
    // stage s2p for this tile
    {
      int j = t >> 3, k = t & 7;
      const float* row = &S2[(size_t)(jb + j) * 64 + k * 8];
      float4 u0 = *(const float4*)row;
      float4 u1 = *(const float4*)(row + 4);
      s2p[0][j][k] = u0.x; s2p[1][j][k] = u0.y;
      s2p[2][j][k] = u0.z; s2p[3][j][k] = u0.w;
      s2p[4][j][k] = u1.x; s2p[5][j][k] = u1.y;
      s2p[6][j][k] = u1.z; s2p[7][j][k] = u1.w;
    }
    __syncthreads();

    // consume prefetched E; issue next tile's E loads early
    int4 ca0 = pa0, ca1 = pa1, cb0 = pb0, cb1 = pb1;
    if (jt < 7) {
      int base = jb + 64 + q * 8;
      pa0 = *(const int4*)(Erow + base);
      pa1 = *(const int4*)(Erow + base + 4);
      pb0 = *(const int4*)(Erow + base + 32);
      pb1 = *(const int4*)(Erow + base + 32 + 4);
    }

    // B fragments (global, L2-resident VtH)
    half8 bfrag[4][2];
#pragma unroll
    for (int n = 0; n < 4; ++n)
#pragma unroll
      for (int s = 0; s < 2; ++s) {
        const u16* p = &VtH[(size_t)(w * 64 + n * 16 + li) * NN + jb + s * 32 + q * 8];
        bfrag[n][s] = *(const half8*)p;
      }

    // scores -> A fragments
    const float* s1row = &s1p[w][li][0];
    half8 af0, af1;
    {
      int ed[8] = {ca0.x, ca0.y, ca0.z, ca0.w, ca1.x, ca1.y, ca1.z, ca1.w};
      float ls = 0.f;
#pragma unroll
      for (int e = 0; e < 8; ++e) {
        int edge = ed[e];
        int k = min(max(edge, 0), 7);
        float sv = s1row[k] + s2p[w][q * 8 + e][k];
        float ev = fmaxf(sv, NEG * sv);
        ev = (edge >= 0) ? ev : 0.0f;
        float pv = __expf(ev);
        ls += pv;
        af0[e] = (_Float16)(pv * 0.0625f);
      }
      lsum += ls;
    }
    {
      int ed[8] = {cb0.x, cb0.y, cb0.z, cb0.w, cb1.x, cb1.y, cb1.z, cb1.w};
      float ls = 0.f;
#pragma unroll
      for (int e = 0; e < 8; ++e) {
        int edge = ed[e];
        int k = min(max(edge, 0), 7);
        float sv = s1row[k] + s2p[w][32 + q * 8 + e][k];
        float ev = fmaxf(sv, NEG * sv);
        ev = (edge >= 0) ? ev : 0.0f;
        float pv = __expf(ev);
        ls += pv;
        af1[e] = (_Float16)(pv * 0.0625f);
      }
      lsum += ls;
    }

    // MFMA: acc[n] += A[s] x B[n][s]
#pragma unroll
    for (int n = 0; n < 4; ++n) {
      acc[n] = __builtin_amdgcn_mfma_f32_16x16x32_f16(af0, bfrag[n][0], acc[n], 0, 0, 0);
      acc[n] = __builtin_amdgcn_mfma_f32_16x16x32_f16(af1, bfrag[n][1], acc[n], 0, 0, 0);
    }

    __syncthreads();
  }

  // denominator: lanes {li, li+16, li+32, li+48} share row li -> reduce over q
  lsum += __shfl_xor(lsum, 16);
  lsum += __shfl_xor(lsum, 32);
  if (q == 0) {
    LPART[((size_t)ch * NN + i0 + li) * 8 + w] = lsum;
  }

  // store partial numerators. C layout: col = lane&15, row = (lane>>4)*4 + reg
  float* base = PART + (size_t)ch * NN * DD;
#pragma unroll
  for (int n = 0; n < 4; ++n) {
#pragma unroll
    for (int r = 0; r < 4; ++r) {
      int row = i0 + q * 4 + r;
      int col = w * 64 + n * 16 + li;
      base[(size_t)row * DD + col] = acc[n][r];
    }
  }
}

// ---------------------------------------------------------------------------
// Kernel 4: combine 4 j-chunk partials, divide by denominator (x16 for the
// f16 P scaling), project with Pw + Pb. grid 512 (4 rows), block 256.
// ---------------------------------------------------------------------------
__global__ __launch_bounds__(256) void proj_kernel(
    const float* __restrict__ PART, const float* __restrict__ LPART,
    const float* __restrict__ Pw, const float* __restrict__ Pb,
    float* __restrict__ out) {
  __shared__ __align__(16) float preS[4][512];
  __shared__ float linv[4][8];
  int t = threadIdx.x;
  int r0 = blockIdx.x * 4;
  if (t < 32) {
    int i = t >> 3, h = t & 7;
    float s = 0.f;
#pragma unroll
    for (int c = 0; c < 4; ++c)
      s += LPART[(size_t)c * NN * 8 + (size_t)(r0 + i) * 8 + h];
    linv[i][h] = 16.0f / s;
  }
  __syncthreads();
  for (int idx = t; idx < 4 * 128; idx += 256) {
    int i = idx >> 7, hd = (idx & 127) * 4;
    float4 v = {0.f, 0.f, 0.f, 0.f};
#pragma unroll
    for (int c = 0; c < 4; ++c) {
      float4 p = *(const float4*)&PART[(size_t)c * NN * DD + (size_t)(r0 + i) * DD + hd];
      v.x += p.x; v.y += p.y; v.z += p.z; v.w += p.w;
    }
    float li2 = linv[i][hd >> 6];
    v.x *= li2; v.y *= li2; v.z *= li2; v.w *= li2;
    *(float4*)&preS[i][hd] = v;
  }
  __syncthreads();
  int c = t & 63, rq = t >> 6;   // rq 0..3 -> one row each
  float acc0 = Pb[c];
  for (int hq = 0; hq < 128; ++hq) {
    int hd = hq * 4;
    float4 p0 = *(const float4*)&preS[rq][hd];
    float w0 = Pw[(hd + 0) * 64 + c];
    float w1 = Pw[(hd + 1) * 64 + c];
    float w2 = Pw[(hd + 2) * 64 + c];
    float w3 = Pw[(hd + 3) * 64 + c];
    acc0 += p0.x * w0 + p0.y * w1 + p0.z * w2 + p0.w * w3;
  }
  out[(size_t)(r0 + rq) * 64 + c] = acc0;
}

// ---------------------------------------------------------------------------
extern "C" void kernel_launch(void* const* d_in, const int* in_sizes, int n_in,
                              void* d_out, int out_size, void* d_ws, size_t ws_size,
                              hipStream_t stream) {
  const float* X  = (const float*)d_in[0];
  const int*   E  = (const int*)d_in[1];
  const float* Qw = (const float*)d_in[2];
  const float* Qb = (const float*)d_in[3];
  const float* Kw = (const float*)d_in[4];
  const float* Kb = (const float*)d_in[5];
  const float* Vw = (const float*)d_in[6];
  const float* Vb = (const float*)d_in[7];
  const float* A  = (const float*)d_in[8];
  const float* Pw = (const float*)d_in[9];
  const float* Pb = (const float*)d_in[10];
  float* out = (float*)d_out;

  float* ws = (float*)d_ws;
  const size_t ND = (size_t)NN * DD;            // 1M floats
  // Region layout (floats). PART aliases Q/K (dead once s12 has run).
  float* Q     = ws;                            // [0, 1M)
  float* K     = ws + ND;                       // [1M, 2M)
  float* PART  = ws;                            // [0, 4M)  (4 chunks x 1M)
  float* S1    = ws + 4 * ND;                   // 128K
  float* S2    = S1 + (size_t)NN * 64;          // 128K
  u16*   VtH   = (u16*)(S2 + (size_t)NN * 64);  // 1M u16 = 512K floats
  float* LPART = (float*)(VtH + (size_t)DD * NN); // 64K floats

  qkv_kernel<<<384, 256, 0, stream>>>(X, Qw, Qb, Kw, Kb, Vw, Vb, Q, K, VtH);
  s12_kernel<<<512, 256, 0, stream>>>(Q, K, A, S1, S2);
  attn_mfma_kernel<<<512, 512, 0, stream>>>(E, S1, S2, VtH, PART, LPART);
  proj_kernel<<<512, 256, 0, stream>>>(PART, LPART, Pw, Pb, out);
}